// Round 10
// baseline (287.144 us; speedup 1.0000x reference)
//
#include <hip/hip_runtime.h>
#include <hip/hip_cooperative_groups.h>

namespace cg = cooperative_groups;

#define BB 64
#define SS 512
#define DD 768
#define D4 192     // DD/4
#define TWU (BB * 12)   // 768 tw tiles
#define AU  2048        // phase-A units (768 tw + 1280 warm)
#define BU  2048        // phase-B units (64 b x 32 chunks)

typedef float v4f __attribute__((ext_vector_type(4)));

// ---------------- fused cooperative kernel ----------------
// Phase A (grid-stride over 2048 units):
//   units 0..767    -> tW tile (one b, 64 d's, 16-way k-split; R4-proven layout)
//   units 768..2047 -> warm 8 seq rows each into L2/L3 (1 dword per 128B line)
// Phase B: 2048 units -> 16 scores each (tW row hoisted to regs, 1 wave : 4 s)
// Phase C: 64 rows -> softmax over S=512 with 256 threads
__global__ __launch_bounds__(256, 8)
void fused_kernel(const float* __restrict__ topic,
                  const float* __restrict__ seq,
                  const float* __restrict__ W,
                  const float* __restrict__ bias,
                  float* __restrict__ out,
                  float* __restrict__ tW,
                  float* __restrict__ scores) {
    __shared__ float  t_s[DD];          // 3 KB
    __shared__ float4 red[16][16];      // 4 KB
    __shared__ float  sred[4];
    __shared__ float  s_m, s_sum;

    const int t    = threadIdx.x;
    const int wv   = t >> 6;
    const int lane = t & 63;
    const int G    = gridDim.x;
    cg::grid_group grid = cg::this_grid();

    // ---------------- Phase A ----------------
    for (int unit = blockIdx.x; unit < AU; unit += G) {
        __syncthreads();                 // protect t_s reuse across iterations
        if (unit < TWU) {
            const int b  = unit / 12;
            const int dt = unit % 12;
            const int d4 = dt * 16;
            const int dl = t & 15;
            const int kg = t >> 4;       // 0..15

            for (int k = t; k < DD; k += 256) t_s[k] = topic[b * DD + k];
            __syncthreads();

            const float4* __restrict__ W4 = (const float4*)W;   // [DD][D4]
            const int k0 = kg * 48;
            float4 acc = make_float4(0.f, 0.f, 0.f, 0.f);
#pragma unroll 6
            for (int k = 0; k < 48; ++k) {
                const float ts = t_s[k0 + k];
                const float4 w = W4[(size_t)(k0 + k) * D4 + d4 + dl];
                acc.x = fmaf(ts, w.x, acc.x);
                acc.y = fmaf(ts, w.y, acc.y);
                acc.z = fmaf(ts, w.z, acc.z);
                acc.w = fmaf(ts, w.w, acc.w);
            }
            red[kg][dl] = acc;
            __syncthreads();

            if (t < 16) {
                float4 s = red[0][t];
#pragma unroll
                for (int j = 1; j < 16; ++j) {
                    const float4 r = red[j][t];
                    s.x += r.x; s.y += r.y; s.z += r.z; s.w += r.w;
                }
                ((float4*)tW)[(size_t)b * D4 + d4 + t] = s;
            }
        } else {
            // Warm 8 seq rows: 8*3072 B = 192 lines of 128 B, 1 dword each.
            const int pid = unit - TWU;               // 0..1279
            const size_t base = (size_t)pid * 8 * DD; // floats
            float keep = 0.f;
            if (t < 192) keep = seq[base + (size_t)t * 32];
            asm volatile("" :: "v"(keep));            // keep load live (no DCE)
        }
    }

    grid.sync();

    // ---------------- Phase B: scores ----------------
    for (int unit = blockIdx.x; unit < BU; unit += G) {
        const int b     = unit >> 5;
        const int chunk = unit & 31;
        const float4* tp = (const float4*)(tW + (size_t)b * DD);
        const float4 t0 = tp[lane];
        const float4 t1 = tp[lane + 64];
        const float4 t2 = tp[lane + 128];
        const float  bb = bias[0];

        const int s0 = chunk * 16 + wv * 4;
#pragma unroll
        for (int i = 0; i < 4; ++i) {
            const int s = s0 + i;
            const float4* sp = (const float4*)(seq + ((size_t)b * SS + s) * DD);
            const float4 x0 = sp[lane];
            const float4 x1 = sp[lane + 64];
            const float4 x2 = sp[lane + 128];

            float acc = 0.f;
            acc = fmaf(x0.x, t0.x, acc); acc = fmaf(x0.y, t0.y, acc);
            acc = fmaf(x0.z, t0.z, acc); acc = fmaf(x0.w, t0.w, acc);
            acc = fmaf(x1.x, t1.x, acc); acc = fmaf(x1.y, t1.y, acc);
            acc = fmaf(x1.z, t1.z, acc); acc = fmaf(x1.w, t1.w, acc);
            acc = fmaf(x2.x, t2.x, acc); acc = fmaf(x2.y, t2.y, acc);
            acc = fmaf(x2.z, t2.z, acc); acc = fmaf(x2.w, t2.w, acc);

#pragma unroll
            for (int off = 32; off >= 1; off >>= 1) acc += __shfl_xor(acc, off);

            if (lane == 0) scores[(size_t)b * SS + s] = acc + bb;
        }
    }

    grid.sync();

    // ---------------- Phase C: softmax ----------------
    for (int b = blockIdx.x; b < BB; b += G) {
        __syncthreads();                 // protect sred/s_m/s_sum reuse
        const float v0 = scores[(size_t)b * SS + t];
        const float v1 = scores[(size_t)b * SS + t + 256];

        float m = fmaxf(v0, v1);
#pragma unroll
        for (int off = 32; off >= 1; off >>= 1) m = fmaxf(m, __shfl_xor(m, off));
        if (lane == 0) sred[wv] = m;
        __syncthreads();
        if (t == 0) s_m = fmaxf(fmaxf(sred[0], sred[1]), fmaxf(sred[2], sred[3]));
        __syncthreads();

        const float e0 = __expf(v0 - s_m);
        const float e1 = __expf(v1 - s_m);
        float sum = e0 + e1;
#pragma unroll
        for (int off = 32; off >= 1; off >>= 1) sum += __shfl_xor(sum, off);
        if (lane == 0) sred[wv] = sum;
        __syncthreads();
        if (t == 0) s_sum = (sred[0] + sred[1]) + (sred[2] + sred[3]);
        __syncthreads();

        const float inv = 1.f / s_sum;
        out[(size_t)b * SS + t]       = e0 * inv;
        out[(size_t)b * SS + t + 256] = e1 * inv;
    }
}

// ---------------- fallback path (R4-proven, 30.4 us) ----------------
__global__ void tw_kernel(const float* __restrict__ topic,
                          const float* __restrict__ W,
                          float* __restrict__ tW) {
    __shared__ float t_s[DD];
    __shared__ float4 red[16][16];
    const int b  = blockIdx.x;
    const int t  = threadIdx.x;
    const int dl = t & 15;
    const int kg = t >> 4;
    const int d4 = blockIdx.y * 16;

    for (int k = t; k < DD; k += 256) t_s[k] = topic[b * DD + k];
    __syncthreads();

    const float4* __restrict__ W4 = (const float4*)W;
    const int k0 = kg * 48;
    float4 acc = make_float4(0.f, 0.f, 0.f, 0.f);
#pragma unroll 8
    for (int k = 0; k < 48; ++k) {
        const float ts = t_s[k0 + k];
        const float4 w = W4[(size_t)(k0 + k) * D4 + d4 + dl];
        acc.x = fmaf(ts, w.x, acc.x);
        acc.y = fmaf(ts, w.y, acc.y);
        acc.z = fmaf(ts, w.z, acc.z);
        acc.w = fmaf(ts, w.w, acc.w);
    }
    red[kg][dl] = acc;
    __syncthreads();

    if (t < 16) {
        float4 s = red[0][t];
#pragma unroll
        for (int j = 1; j < 16; ++j) {
            const float4 r = red[j][t];
            s.x += r.x; s.y += r.y; s.z += r.z; s.w += r.w;
        }
        ((float4*)tW)[(size_t)b * D4 + d4 + t] = s;
    }
}

__global__ void score_kernel(const float* __restrict__ tW,
                             const float* __restrict__ seq,
                             const float* __restrict__ bias,
                             float* __restrict__ scores) {
    const int gwid = (int)((blockIdx.x * blockDim.x + threadIdx.x) >> 6);
    const int lane = threadIdx.x & 63;
    const int b = gwid >> 9;
    const int s = gwid & (SS - 1);

    const v4f* sp = (const v4f*)(seq + ((size_t)b * SS + s) * DD);
    const float4* tp = (const float4*)(tW + (size_t)b * DD);

    float acc = 0.f;
#pragma unroll
    for (int k = 0; k < 3; ++k) {
        const v4f x = __builtin_nontemporal_load(sp + lane + k * 64);
        const float4 t = tp[lane + k * 64];
        acc = fmaf(x.x, t.x, acc);
        acc = fmaf(x.y, t.y, acc);
        acc = fmaf(x.z, t.z, acc);
        acc = fmaf(x.w, t.w, acc);
    }
#pragma unroll
    for (int off = 32; off >= 1; off >>= 1) acc += __shfl_xor(acc, off);

    if (lane == 0) scores[gwid] = acc + bias[0];
}

__global__ void softmax_kernel(const float* __restrict__ scores,
                               float* __restrict__ beta) {
    __shared__ float red[8];
    __shared__ float s_m, s_sum;
    const int b   = blockIdx.x;
    const int tid = threadIdx.x;
    const int wid = tid >> 6, lane = tid & 63;

    const float v = scores[b * SS + tid];

    float m = v;
#pragma unroll
    for (int off = 32; off >= 1; off >>= 1) m = fmaxf(m, __shfl_xor(m, off));
    if (lane == 0) red[wid] = m;
    __syncthreads();
    if (tid == 0) {
        float mm = red[0];
#pragma unroll
        for (int i = 1; i < 8; ++i) mm = fmaxf(mm, red[i]);
        s_m = mm;
    }
    __syncthreads();

    const float e = __expf(v - s_m);
    float sum = e;
#pragma unroll
    for (int off = 32; off >= 1; off >>= 1) sum += __shfl_xor(sum, off);
    if (lane == 0) red[wid] = sum;
    __syncthreads();
    if (tid == 0) {
        float ss = 0.f;
#pragma unroll
        for (int i = 0; i < 8; ++i) ss += red[i];
        s_sum = ss;
    }
    __syncthreads();

    beta[b * SS + tid] = e / s_sum;
}

extern "C" void kernel_launch(void* const* d_in, const int* in_sizes, int n_in,
                              void* d_out, int out_size, void* d_ws, size_t ws_size,
                              hipStream_t stream) {
    const float* topic = (const float*)d_in[0];
    const float* seq   = (const float*)d_in[1];
    const float* W     = (const float*)d_in[2];
    const float* bias  = (const float*)d_in[3];
    float* out = (float*)d_out;

    float* tW     = (float*)d_ws;                 // BB*DD floats
    float* scores = tW + (size_t)BB * DD;         // BB*SS floats

    // Size the cooperative grid from actual occupancy (host-only queries,
    // capture-safe, deterministic).
    int dev = 0;
    (void)hipGetDevice(&dev);
    int numCU = 256;
    (void)hipDeviceGetAttribute(&numCU, hipDeviceAttributeMultiprocessorCount, dev);
    int maxPerCU = 0;
    hipError_t oe = hipOccupancyMaxActiveBlocksPerMultiprocessor(
        &maxPerCU, (const void*)fused_kernel, 256, 0);

    hipError_t le = hipErrorUnknown;
    if (oe == hipSuccess && maxPerCU > 0 && numCU > 0) {
        int gridSz = maxPerCU * numCU;
        if (gridSz > AU) gridSz = AU;
        void* args[] = { (void*)&topic, (void*)&seq, (void*)&W, (void*)&bias,
                         (void*)&out, (void*)&tW, (void*)&scores };
        le = hipLaunchCooperativeKernel((const void*)fused_kernel,
                                        dim3(gridSz), dim3(256), args, 0, stream);
    }

    if (le != hipSuccess) {
        // Deterministic fallback: proven 3-kernel path.
        tw_kernel<<<dim3(BB, 12), 256, 0, stream>>>(topic, W, tW);
        const int total_waves = BB * SS;
        const int blocks = (total_waves * 64) / 256;
        score_kernel<<<blocks, 256, 0, stream>>>(tW, seq, bias, scores);
        softmax_kernel<<<BB, 512, 0, stream>>>(scores, out);
    }
}